// Round 6
// baseline (95.154 us; speedup 1.0000x reference)
//
#include <hip/hip_runtime.h>

// out[b][s][d] = W[d][s] + bias[d]  for b in [0,4), s in [0,4096), d in [0,1024)
// ALL f32. W is [1024, 8192] row-major (row stride ML=8192 floats). x unused:
// one_hot(arange(S)) @ W.T + b is a row-gather = transpose of W[:, :S] + bias.
//
// Write-BW-bound transpose: 64x64 LDS tile, coalesced float4 in/out,
// 4x batch broadcast from one LDS read.
// Roofline: 16 MiB read + 64 MiB write @ ~6.4 TB/s (measured via harness fills) ~= 13 us.
// NOTE: bench dur_us (~95) includes harness poison-fills (256 MiB @ ~42 us each in
// top-5); kernel itself is <41.6 us (absent from top-5 which sorts by duration).
//
// LDS layout (r5): XOR swizzle at float4-group granularity, element (srow,d) at word
//   srow*64 + (((d>>2) ^ ((srow>>2)&7)) * 4) + (d&3)
// -> scatter-write banks per instr: 4*(((w+4p)^(sv&7))&7) + (dr&3) = 32 banks x 2 lanes
//    (2-way aliasing is free, m136); b128 reads hit all 8 bank-clusters uniformly.
// Bijective group permutation per row -> same data, no pad (16 KB LDS).

#define S_DIM 4096
#define D_DIM 1024
#define ML    8192
#define BATCH 4
#define TILE  64

__global__ __launch_bounds__(256) void pos_emb_kernel(const float* __restrict__ W,
                                                      const float* __restrict__ bias,
                                                      float* __restrict__ out) {
    __shared__ float tile[TILE * TILE];  // 16 KB, group-swizzled

    const int tid = threadIdx.x;
    const int s0  = (int)(blockIdx.x & 63) * TILE;  // 64 s-tiles
    const int d0  = (int)(blockIdx.x >> 6) * TILE;  // 16 d-tiles

    // ---- Load phase: coalesced along s, swizzled scatter into LDS ----
    // sv = float4 index along s (0..15), dr = d row (0..15), 4 passes over d
    const int sv = tid & 15;
    const int dr = tid >> 4;
    #pragma unroll
    for (int p = 0; p < 4; ++p) {
        const int d = dr + p * 16;
        const float4 v = *reinterpret_cast<const float4*>(
            &W[(size_t)(d0 + d) * ML + (size_t)s0 + sv * 4]);
        const int G   = (d >> 2) ^ (sv & 7);  // swizzled group; (srow>>2)&7 == sv&7 for all k
        const int off = d & 3;
        const float vv[4] = {v.x, v.y, v.z, v.w};
        #pragma unroll
        for (int k = 0; k < 4; ++k) {
            const int srow = sv * 4 + k;
            tile[srow * TILE + G * 4 + off] = vv[k];
        }
    }

    // ---- Bias for write-phase d-slice (independent of LDS, overlaps latency) ----
    const int dv = tid & 15;   // float4 group along d (0..15)
    const int sr = tid >> 4;   // s row (0..15), 4 passes over s
    const float4 bvec = *reinterpret_cast<const float4*>(&bias[d0 + dv * 4]);

    __syncthreads();

    // ---- Write phase: swizzled b128 LDS read, coalesced float4 stores x4 batches ----
    #pragma unroll
    for (int p = 0; p < 4; ++p) {
        const int s = sr + p * 16;
        const int G = dv ^ ((s >> 2) & 7);    // un-swizzle logical group dv of row s
        float4 v = *reinterpret_cast<const float4*>(&tile[s * TILE + G * 4]);
        v.x += bvec.x; v.y += bvec.y; v.z += bvec.z; v.w += bvec.w;
        const size_t o = (size_t)(s0 + s) * D_DIM + (size_t)d0 + dv * 4;
        #pragma unroll
        for (int b = 0; b < BATCH; ++b) {
            *reinterpret_cast<float4*>(&out[(size_t)b * S_DIM * D_DIM + o]) = v;
        }
    }
}

extern "C" void kernel_launch(void* const* d_in, const int* in_sizes, int n_in,
                              void* d_out, int out_size, void* d_ws, size_t ws_size,
                              hipStream_t stream) {
    // inputs: [0] x (unused, f32), [1] W [1024*8192] f32, [2] b [1024] f32
    const float* W = (const float*)d_in[1];
    const float* b = (const float*)d_in[2];
    float* out     = (float*)d_out;

    const int grid = (S_DIM / TILE) * (D_DIM / TILE);  // 64 * 16 = 1024
    pos_emb_kernel<<<dim3(grid), dim3(256), 0, stream>>>(W, b, out);
}